// Round 4
// baseline (643.561 us; speedup 1.0000x reference)
//
#include <hip/hip_runtime.h>
#include <math.h>

// ---------------------------------------------------------------------------
// MemoryRetriever: B=8, S=2048 (N=16384 rows), H=1024, M=256, NH=4, HD=64,
// NM=4096, K_SEL=512. fp32 I/O, bf16 MFMA internals.
// R4: flash-fused attention (S+softmax+PV in one kernel), BM=64 GEMM variant
//     for occupancy-starved Q/attn projections, gate-mult fused into int_w2.
// ---------------------------------------------------------------------------

typedef __bf16 bf16x8 __attribute__((ext_vector_type(8)));
typedef __bf16 bf16x4 __attribute__((ext_vector_type(4)));
typedef float  floatx4 __attribute__((ext_vector_type(4)));

#define NMEM   4096
#define KSEL   512

__device__ __forceinline__ void gl_lds16(const __bf16* g, __bf16* l) {
  __builtin_amdgcn_global_load_lds(
      (const __attribute__((address_space(1))) void*)g,
      (__attribute__((address_space(3))) void*)l, 16, 0, 0);
}

// ---------------------------------------------------------------------------
// 1) fp32 -> bf16 conversion of qh + big weights
// ---------------------------------------------------------------------------
__global__ void cvt_kernel(const float* __restrict__ s0, const float* __restrict__ s1,
                           const float* __restrict__ s2, const float* __restrict__ s3,
                           const float* __restrict__ s4,
                           __bf16* __restrict__ d0, __bf16* __restrict__ d1,
                           __bf16* __restrict__ d2, __bf16* __restrict__ d3,
                           __bf16* __restrict__ d4) {
  long q = (long)blockIdx.x * 256 + threadIdx.x;  // quad index
  const long n0 = 16777216 / 4, n1 = 65536 / 4, n2 = 1310720 / 4,
             n3 = 2621440 / 4, n4 = 2097152 / 4;
  const float* s; __bf16* d; long off;
  if (q < n0) { s = s0; d = d0; off = q; }
  else if ((q -= n0) < n1) { s = s1; d = d1; off = q; }
  else if ((q -= n1) < n2) { s = s2; d = d2; off = q; }
  else if ((q -= n2) < n3) { s = s3; d = d3; off = q; }
  else if ((q -= n3) < n4) { s = s4; d = d4; off = q; }
  else return;
  float4 v = ((const float4*)s)[off];
  bf16x4 o;
  o[0] = (__bf16)v.x; o[1] = (__bf16)v.y; o[2] = (__bf16)v.z; o[3] = (__bf16)v.w;
  ((bf16x4*)d)[off] = o;
}

// ---------------------------------------------------------------------------
// 2) top-512 of 4096 scores: radix-select on order-mapped float bits.
// ---------------------------------------------------------------------------
__device__ __forceinline__ unsigned mapbits(float x) {
  unsigned b = __float_as_uint(x);
  return (b & 0x80000000u) ? ~b : (b | 0x80000000u);
}

__global__ void topk_kernel(const float* __restrict__ scores, int* __restrict__ idx_out) {
  const int n = NMEM, k = KSEL;
  __shared__ int hist[256];
  __shared__ int s_need;
  __shared__ unsigned s_prefix;
  __shared__ int s_cnt_gt, s_ntie;
  __shared__ int tie[1024];
  int tid = threadIdx.x;  // 256 threads
  if (tid == 0) { s_need = k; s_prefix = 0; s_cnt_gt = 0; s_ntie = 0; }
  __syncthreads();
  for (int pass = 0; pass < 4; ++pass) {
    if (tid < 256) hist[tid] = 0;
    __syncthreads();
    int shift = 24 - 8 * pass;
    unsigned pref = s_prefix;
    for (int i = tid; i < n; i += 256) {
      unsigned u = mapbits(scores[i]);
      bool in = (pass == 0) || ((u >> (shift + 8)) == pref);
      if (in) atomicAdd(&hist[(u >> shift) & 255], 1);
    }
    __syncthreads();
    if (tid == 0) {
      int need = s_need, above = 0, b = 255;
      for (;; --b) {
        int c = hist[b];
        if (above + c >= need) { s_need = need - above; break; }
        above += c;
      }
      s_prefix = (s_prefix << 8) | (unsigned)b;
    }
    __syncthreads();
  }
  unsigned T = s_prefix;
  int need = s_need;
  for (int i = tid; i < n; i += 256) {
    unsigned u = mapbits(scores[i]);
    if (u > T) { int p = atomicAdd(&s_cnt_gt, 1); idx_out[p] = i; }
    else if (u == T) { int t = atomicAdd(&s_ntie, 1); if (t < 1024) tie[t] = i; }
  }
  __syncthreads();
  int base = s_cnt_gt;
  int nt = s_ntie < 1024 ? s_ntie : 1024;
  for (int j = tid; j < nt; j += 256) {
    int my = tie[j], rank = 0;
    for (int l = 0; l < nt; ++l) rank += (tie[l] < my) ? 1 : 0;
    if (rank < need) idx_out[base + rank] = my;
  }
}

// ---------------------------------------------------------------------------
// 3) Wc = 0.125 * (wq @ qp_w)  [256 x 1024] bf16 ;  bcq = 0.125*(wq@qp_b + bq)
// ---------------------------------------------------------------------------
__global__ void wc_build(const float* __restrict__ qp_w, const float* __restrict__ qp_b,
                         const float* __restrict__ in_w, const float* __restrict__ in_b,
                         __bf16* __restrict__ Wc, float* __restrict__ bcq) {
  int i = blockIdx.x, t = threadIdx.x;  // 256 blocks x 256 threads
  const float* wq = in_w + (long)i * 256;
  float a0 = 0, a1 = 0, a2 = 0, a3 = 0;
  for (int s = 0; s < 256; ++s) {
    float wv = wq[s];
    const float* qr = qp_w + (long)s * 1024 + t;
    a0 += wv * qr[0];   a1 += wv * qr[256];
    a2 += wv * qr[512]; a3 += wv * qr[768];
  }
  __bf16* wr = Wc + (long)i * 1024 + t;
  wr[0]   = (__bf16)(0.125f * a0); wr[256] = (__bf16)(0.125f * a1);
  wr[512] = (__bf16)(0.125f * a2); wr[768] = (__bf16)(0.125f * a3);
  if (t == 0) {
    float s = in_b[i];
    for (int j = 0; j < 256; ++j) s += wq[j] * qp_b[j];
    bcq[i] = 0.125f * s;
  }
}

// ---------------------------------------------------------------------------
// 4) gather + LN(ln1) + K / V projections. K row-major [512,256] bf16;
//    V transposed: Vt[h][d][key] = [4][64][512] bf16.
// ---------------------------------------------------------------------------
__global__ void kv_build(const int* __restrict__ idx, const float* __restrict__ mem_keys,
                         const float* __restrict__ in_w, const float* __restrict__ in_b,
                         const float* __restrict__ ln1g, const float* __restrict__ ln1b,
                         __bf16* __restrict__ Kmat, __bf16* __restrict__ Vt) {
  int r = blockIdx.x, t = threadIdx.x;  // 512 blocks x 256 threads
  int lane = t & 63, wave = t >> 6;
  __shared__ float wred[8];
  __shared__ float m[256];
  int row = idx[r];
  float x = mem_keys[(long)row * 256 + t];
  float s = x;
  #pragma unroll
  for (int o = 32; o > 0; o >>= 1) s += __shfl_xor(s, o);
  if (lane == 0) wred[wave] = s;
  __syncthreads();
  float mu = (wred[0] + wred[1] + wred[2] + wred[3]) / 256.0f;
  float e = x - mu;
  s = e * e;
  #pragma unroll
  for (int o = 32; o > 0; o >>= 1) s += __shfl_xor(s, o);
  if (lane == 0) wred[4 + wave] = s;
  __syncthreads();
  float rstd = rsqrtf((wred[4] + wred[5] + wred[6] + wred[7]) / 256.0f + 1e-5f);
  m[t] = e * rstd * ln1g[t] + ln1b[t];
  __syncthreads();
  float ka = 0.f, va = 0.f;
  const float* wk = in_w + (long)(256 + t) * 256;
  const float* wv = in_w + (long)(512 + t) * 256;
  #pragma unroll 4
  for (int i = 0; i < 256; i += 4) {
    float4 wkv = *(const float4*)(wk + i);
    float4 wvv = *(const float4*)(wv + i);
    ka += m[i] * wkv.x + m[i + 1] * wkv.y + m[i + 2] * wkv.z + m[i + 3] * wkv.w;
    va += m[i] * wvv.x + m[i + 1] * wvv.y + m[i + 2] * wvv.z + m[i + 3] * wvv.w;
  }
  ka += in_b[256 + t]; va += in_b[512 + t];
  Kmat[(long)r * 256 + t] = (__bf16)ka;
  Vt[(long)(t >> 6) * (64 * 512) + (long)(t & 63) * 512 + r] = (__bf16)va;
}

// ---------------------------------------------------------------------------
// 5) m97-style bf16 MFMA GEMM with XOR-swizzled LDS.
//    EPI: 0=bias, 1=none, 2=bias+sigmoid, 3=bias then *gmul (gated output).
// ---------------------------------------------------------------------------
template <int BM, int BN, int EPI>
__launch_bounds__(256, 4)
__global__ void gemm_kernel(const __bf16* __restrict__ X1, int ldx1, int K1,
                            const __bf16* __restrict__ X2, int ldx2,
                            const __bf16* __restrict__ W, int ldw,
                            const float* __restrict__ bias,
                            const __bf16* __restrict__ gmul,
                            __bf16* __restrict__ C, int ldc, int Ktot,
                            long sXz, long sWz, long sCz) {
  constexpr int BK = 64;
  __shared__ __bf16 As[BM * BK];
  __shared__ __bf16 Bs[BN * BK];
  const int tid = threadIdx.x;
  const int lane = tid & 63, wave = tid >> 6;
  const int wm = wave >> 1, wn = wave & 1;
  constexpr int FM = (BM / 2) / 16, FN = (BN / 2) / 16;
  floatx4 acc[FM][FN];
  #pragma unroll
  for (int i = 0; i < FM; ++i)
    #pragma unroll
    for (int j = 0; j < FN; ++j)
      #pragma unroll
      for (int r = 0; r < 4; ++r) acc[i][j][r] = 0.0f;

  const long z = blockIdx.z;
  const __bf16* x1 = X1 + z * sXz;
  const __bf16* w  = W + z * sWz;
  __bf16* c = C + z * sCz;
  const long row0 = (long)blockIdx.x * BM;
  const int col0 = blockIdx.y * BN;
  const int nKt = Ktot / BK;
  const int srow = lane >> 3;                    // 0..7 : row within 8-row chunk
  const int scol = ((lane & 7) ^ srow) * 8;      // XOR-swizzled col chunk

  for (int kt = 0; kt < nKt; ++kt) {
    const int k0 = kt * BK;
    const __bf16* xb; long xld; int kx;  // segment select (wave-uniform)
    if (k0 < K1) { xb = x1; xld = ldx1; kx = k0; }
    else         { xb = X2; xld = ldx2; kx = k0 - K1; }
    #pragma unroll
    for (int i = 0; i < BM / 32; ++i) {  // A: chunks of 8 rows x 64 cols
      int chunk = wave * (BM / 32) + i;
      const __bf16* g = xb + (row0 + chunk * 8 + srow) * xld + kx + scol;
      gl_lds16(g, As + chunk * 512);
    }
    #pragma unroll
    for (int i = 0; i < BN / 32; ++i) {
      int chunk = wave * (BN / 32) + i;
      const __bf16* g = w + (long)(col0 + chunk * 8 + srow) * ldw + k0 + scol;
      gl_lds16(g, Bs + chunk * 512);
    }
    __syncthreads();
    #pragma unroll
    for (int kk = 0; kk < 2; ++kk) {
      bf16x8 a[FM], b[FN];
      const int ccq = kk * 4 + (lane >> 4);      // col-chunk index 0..7
      #pragma unroll
      for (int fm = 0; fm < FM; ++fm) {
        const int r = wm * (BM / 2) + fm * 16 + (lane & 15);
        a[fm] = *(const bf16x8*)(As + r * BK + ((ccq ^ (r & 7)) << 3));
      }
      #pragma unroll
      for (int fn = 0; fn < FN; ++fn) {
        const int r = wn * (BN / 2) + fn * 16 + (lane & 15);
        b[fn] = *(const bf16x8*)(Bs + r * BK + ((ccq ^ (r & 7)) << 3));
      }
      #pragma unroll
      for (int fm = 0; fm < FM; ++fm)
        #pragma unroll
        for (int fn = 0; fn < FN; ++fn)
          acc[fm][fn] = __builtin_amdgcn_mfma_f32_16x16x32_bf16(a[fm], b[fn], acc[fm][fn], 0, 0, 0);
    }
    __syncthreads();
  }
  // epilogue: C/D layout col = lane&15, row = (lane>>4)*4 + r
  #pragma unroll
  for (int fn = 0; fn < FN; ++fn) {
    const int col = col0 + wn * (BN / 2) + fn * 16 + (lane & 15);
    float bv = (EPI == 1) ? 0.0f : bias[col];
    #pragma unroll
    for (int fm = 0; fm < FM; ++fm) {
      #pragma unroll
      for (int r = 0; r < 4; ++r) {
        long row = row0 + wm * (BM / 2) + fm * 16 + (lane >> 4) * 4 + r;
        float v = acc[fm][fn][r] + bv;
        if (EPI == 2) v = 1.0f / (1.0f + __expf(-v));
        if (EPI == 3) v *= (float)gmul[row * (long)ldc + col];
        c[row * (long)ldc + col] = (__bf16)v;
      }
    }
  }
}

// ---------------------------------------------------------------------------
// 6) Flash-fused attention: per (64-row tile, head): S = Q·K^T (scale folded
//    into Q), online softmax, O = P·V. K/V processed in 4 chunks of 128 keys.
//    Waves 2x2: wm = row-half (32 rows), wn = key-half (64 keys) for S /
//    d-half (32 dims) for O. P round-trips through LDS (C-layout -> A-layout).
//    All LDS XOR-swizzled by 16B chunks (2-way = free).
// ---------------------------------------------------------------------------
__launch_bounds__(256, 2)
__global__ void flash_kernel(const __bf16* __restrict__ Q, const __bf16* __restrict__ Km,
                             const __bf16* __restrict__ Vt, __bf16* __restrict__ Ctx) {
  __shared__ __bf16 Qs[64 * 64];    //  8 KB
  __shared__ __bf16 Ks[128 * 64];   // 16 KB (key chunk)
  __shared__ __bf16 Vs[64 * 128];   // 16 KB (d-major, key cols)
  __shared__ __bf16 Ps[64 * 128];   // 16 KB
  __shared__ float mpart[2][64], spart[2][64];
  __shared__ float m_run[64], l_run[64];
  const int tid = threadIdx.x, lane = tid & 63, wave = tid >> 6;
  const int wm = wave >> 1, wn = wave & 1;
  const long row0 = (long)blockIdx.x * 64;
  const int h = blockIdx.y;
  const int srow = lane >> 3, scc = lane & 7;
  const int q4 = lane >> 4, l15 = lane & 15;

  if (tid < 64) { m_run[tid] = -3e38f; l_run[tid] = 0.f; }
  // stage Q tile: 64 rows x 64 cols from Q[row][h*64+..]
  #pragma unroll
  for (int i = 0; i < 2; ++i) {
    int chunk = wave * 2 + i;  // 0..7, 8 rows each
    int r = chunk * 8 + srow;
    gl_lds16(Q + (row0 + r) * 256 + h * 64 + ((scc ^ (r & 7)) << 3), Qs + chunk * 512);
  }
  floatx4 oacc[2][2];
  #pragma unroll
  for (int fm = 0; fm < 2; ++fm)
    #pragma unroll
    for (int fn = 0; fn < 2; ++fn)
      #pragma unroll
      for (int r = 0; r < 4; ++r) oacc[fm][fn][r] = 0.f;

  for (int c = 0; c < 4; ++c) {
    // stage K chunk (128 keys x 64 dims) and V chunk (64 dims x 128 keys)
    #pragma unroll
    for (int i = 0; i < 4; ++i) {
      int chunk = wave * 4 + i;  // 0..15
      int r = chunk * 8 + srow;
      gl_lds16(Km + (long)(c * 128 + r) * 256 + h * 64 + ((scc ^ (r & 7)) << 3),
               Ks + chunk * 512);
    }
    #pragma unroll
    for (int i = 0; i < 4; ++i) {
      int chunk = wave * 4 + i;  // 0..15, 4 d-rows each
      int d = chunk * 4 + q4;
      int cc = l15 ^ (d & 7);
      gl_lds16(Vt + (long)h * 32768 + (long)d * 512 + c * 128 + cc * 8,
               Vs + chunk * 512);
    }
    __syncthreads();  // staging done (incl. first-iter Qs, stats init)

    // S = Q·Kc^T : per wave 32 rows x 64 keys
    floatx4 sacc[2][4];
    #pragma unroll
    for (int fm = 0; fm < 2; ++fm)
      #pragma unroll
      for (int fn = 0; fn < 4; ++fn)
        #pragma unroll
        for (int r = 0; r < 4; ++r) sacc[fm][fn][r] = 0.f;
    #pragma unroll
    for (int kk = 0; kk < 2; ++kk) {
      bf16x8 a[2], b[4];
      const int ccq = kk * 4 + q4;
      #pragma unroll
      for (int fm = 0; fm < 2; ++fm) {
        const int r = wm * 32 + fm * 16 + l15;
        a[fm] = *(const bf16x8*)(Qs + r * 64 + ((ccq ^ (r & 7)) << 3));
      }
      #pragma unroll
      for (int fn = 0; fn < 4; ++fn) {
        const int r = wn * 64 + fn * 16 + l15;
        b[fn] = *(const bf16x8*)(Ks + r * 64 + ((ccq ^ (r & 7)) << 3));
      }
      #pragma unroll
      for (int fm = 0; fm < 2; ++fm)
        #pragma unroll
        for (int fn = 0; fn < 4; ++fn)
          sacc[fm][fn] = __builtin_amdgcn_mfma_f32_16x16x32_bf16(a[fm], b[fn], sacc[fm][fn], 0, 0, 0);
    }
    // per-row partial max over this wave's 64 keys
    #pragma unroll
    for (int fm = 0; fm < 2; ++fm) {
      #pragma unroll
      for (int r = 0; r < 4; ++r) {
        float v = sacc[fm][0][r];
        #pragma unroll
        for (int fn = 1; fn < 4; ++fn) v = fmaxf(v, sacc[fm][fn][r]);
        v = fmaxf(v, __shfl_xor(v, 1)); v = fmaxf(v, __shfl_xor(v, 2));
        v = fmaxf(v, __shfl_xor(v, 4)); v = fmaxf(v, __shfl_xor(v, 8));
        if (l15 == 0) mpart[wn][wm * 32 + fm * 16 + q4 * 4 + r] = v;
      }
    }
    __syncthreads();  // mpart ready

    // phase A: new max, alpha, P, partial row sums
    float nm[2][4], al[2][4], rs[2][4];
    #pragma unroll
    for (int fm = 0; fm < 2; ++fm)
      #pragma unroll
      for (int r = 0; r < 4; ++r) {
        int row = wm * 32 + fm * 16 + q4 * 4 + r;
        float pm = fmaxf(mpart[0][row], mpart[1][row]);
        float mo = m_run[row];
        float x = fmaxf(mo, pm);
        nm[fm][r] = x;
        al[fm][r] = __expf(mo - x);
        rs[fm][r] = 0.f;
      }
    #pragma unroll
    for (int fm = 0; fm < 2; ++fm)
      #pragma unroll
      for (int fn = 0; fn < 4; ++fn)
        #pragma unroll
        for (int r = 0; r < 4; ++r) {
          float p = __expf(sacc[fm][fn][r] - nm[fm][r]);
          rs[fm][r] += p;
          int row = wm * 32 + fm * 16 + q4 * 4 + r;
          int key = wn * 64 + fn * 16 + l15;
          Ps[row * 128 + (((key >> 3) ^ (row & 7)) << 3) + (key & 7)] = (__bf16)p;
        }
    #pragma unroll
    for (int fm = 0; fm < 2; ++fm)
      #pragma unroll
      for (int r = 0; r < 4; ++r) {
        float v = rs[fm][r];
        v += __shfl_xor(v, 1); v += __shfl_xor(v, 2);
        v += __shfl_xor(v, 4); v += __shfl_xor(v, 8);
        if (l15 == 0) spart[wn][wm * 32 + fm * 16 + q4 * 4 + r] = v;
      }
    __syncthreads();  // spart + Ps ready

    // phase B: update running stats, rescale O, O += P·Vc
    #pragma unroll
    for (int fm = 0; fm < 2; ++fm)
      #pragma unroll
      for (int r = 0; r < 4; ++r) {
        int row = wm * 32 + fm * 16 + q4 * 4 + r;
        if (wn == 0 && l15 == 0) {
          m_run[row] = nm[fm][r];
          l_run[row] = l_run[row] * al[fm][r] + spart[0][row] + spart[1][row];
        }
        #pragma unroll
        for (int fn = 0; fn < 2; ++fn) oacc[fm][fn][r] *= al[fm][r];
      }
    #pragma unroll
    for (int step = 0; step < 4; ++step) {
      bf16x8 a[2], b[2];
      const int ccq = step * 4 + q4;
      #pragma unroll
      for (int fm = 0; fm < 2; ++fm) {
        const int r = wm * 32 + fm * 16 + l15;
        a[fm] = *(const bf16x8*)(Ps + r * 128 + ((ccq ^ (r & 7)) << 3));
      }
      #pragma unroll
      for (int fn = 0; fn < 2; ++fn) {
        const int rv = wn * 32 + fn * 16 + l15;
        b[fn] = *(const bf16x8*)(Vs + rv * 128 + ((ccq ^ (rv & 7)) << 3));
      }
      #pragma unroll
      for (int fm = 0; fm < 2; ++fm)
        #pragma unroll
        for (int fn = 0; fn < 2; ++fn)
          oacc[fm][fn] = __builtin_amdgcn_mfma_f32_16x16x32_bf16(a[fm], b[fn], oacc[fm][fn], 0, 0, 0);
    }
    __syncthreads();  // PV done: Ks/Vs/Ps reusable, stats visible
  }
  // epilogue: ctx = O / l
  #pragma unroll
  for (int fm = 0; fm < 2; ++fm)
    #pragma unroll
    for (int r = 0; r < 4; ++r) {
      int row = wm * 32 + fm * 16 + q4 * 4 + r;
      float inv = 1.0f / l_run[row];
      #pragma unroll
      for (int fn = 0; fn < 2; ++fn) {
        int col = wn * 32 + fn * 16 + l15;
        Ctx[(row0 + row) * 256 + h * 64 + col] = (__bf16)(oacc[fm][fn][r] * inv);
      }
    }
}

// ---------------------------------------------------------------------------
// 7) LN(int_ln) + gelu (tanh form), in-place on t1 rows of 2048.
// ---------------------------------------------------------------------------
__global__ void ln_gelu_kernel(__bf16* __restrict__ T1, const float* __restrict__ g,
                               const float* __restrict__ b) {
  long row = blockIdx.x; int t = threadIdx.x;  // 256 threads, 8 elems each
  int lane = t & 63, wave = t >> 6;
  __shared__ float wred[8];
  __bf16* p = T1 + row * 2048 + t * 8;
  bf16x8 v = *(const bf16x8*)p;
  float f[8], s = 0.f;
  #pragma unroll
  for (int j = 0; j < 8; ++j) { f[j] = (float)v[j]; s += f[j]; }
  #pragma unroll
  for (int o = 32; o > 0; o >>= 1) s += __shfl_xor(s, o);
  if (lane == 0) wred[wave] = s;
  __syncthreads();
  float mu = (wred[0] + wred[1] + wred[2] + wred[3]) / 2048.0f;
  s = 0.f;
  #pragma unroll
  for (int j = 0; j < 8; ++j) { f[j] -= mu; s += f[j] * f[j]; }
  #pragma unroll
  for (int o = 32; o > 0; o >>= 1) s += __shfl_xor(s, o);
  if (lane == 0) wred[4 + wave] = s;
  __syncthreads();
  float rstd = rsqrtf((wred[4] + wred[5] + wred[6] + wred[7]) / 2048.0f + 1e-5f);
  float4 g0 = *(const float4*)(g + t * 8), g1 = *(const float4*)(g + t * 8 + 4);
  float4 b0 = *(const float4*)(b + t * 8), b1 = *(const float4*)(b + t * 8 + 4);
  float gg[8] = { g0.x, g0.y, g0.z, g0.w, g1.x, g1.y, g1.z, g1.w };
  float bb[8] = { b0.x, b0.y, b0.z, b0.w, b1.x, b1.y, b1.z, b1.w };
  bf16x8 o8;
  #pragma unroll
  for (int j = 0; j < 8; ++j) {
    float y = f[j] * rstd * gg[j] + bb[j];
    float u = 1.5957691216057308f * (y + 0.044715f * y * y * y);
    o8[j] = (__bf16)(y / (1.0f + __expf(-u)));
  }
  *(bf16x8*)p = o8;
}

// ---------------------------------------------------------------------------
// 8) out = LN(qh + gi; ln2)  (fp32 out), gi = gate*integrated (pre-fused)
// ---------------------------------------------------------------------------
__global__ void final_kernel(const float* __restrict__ qh, const __bf16* __restrict__ gi,
                             const float* __restrict__ g, const float* __restrict__ b,
                             float* __restrict__ out) {
  long row = blockIdx.x; int t = threadIdx.x;  // 256 threads, 4 elems each
  int lane = t & 63, wave = t >> 6;
  __shared__ float wred[8];
  long base = row * 1024 + t * 4;
  float4 q = *(const float4*)(qh + base);
  bf16x4 gv = *(const bf16x4*)(gi + base);
  float f[4] = { q.x + (float)gv[0], q.y + (float)gv[1],
                 q.z + (float)gv[2], q.w + (float)gv[3] };
  float s = f[0] + f[1] + f[2] + f[3];
  #pragma unroll
  for (int o = 32; o > 0; o >>= 1) s += __shfl_xor(s, o);
  if (lane == 0) wred[wave] = s;
  __syncthreads();
  float mu = (wred[0] + wred[1] + wred[2] + wred[3]) / 1024.0f;
  s = 0.f;
  #pragma unroll
  for (int j = 0; j < 4; ++j) { f[j] -= mu; s += f[j] * f[j]; }
  #pragma unroll
  for (int o = 32; o > 0; o >>= 1) s += __shfl_xor(s, o);
  if (lane == 0) wred[4 + wave] = s;
  __syncthreads();
  float rstd = rsqrtf((wred[4] + wred[5] + wred[6] + wred[7]) / 1024.0f + 1e-5f);
  float4 gv4 = *(const float4*)(g + t * 4);
  float4 bv4 = *(const float4*)(b + t * 4);
  float4 ov;
  ov.x = f[0] * rstd * gv4.x + bv4.x;
  ov.y = f[1] * rstd * gv4.y + bv4.y;
  ov.z = f[2] * rstd * gv4.z + bv4.z;
  ov.w = f[3] * rstd * gv4.w + bv4.w;
  *(float4*)(out + base) = ov;
}

// ---------------------------------------------------------------------------
// launch
// ---------------------------------------------------------------------------
extern "C" void kernel_launch(void* const* d_in, const int* in_sizes, int n_in,
                              void* d_out, int out_size, void* d_ws, size_t ws_size,
                              hipStream_t stream) {
  const float* qh   = (const float*)d_in[0];
  const float* memk = (const float*)d_in[1];
  const float* sel  = (const float*)d_in[2];
  const float* qp_w = (const float*)d_in[3];
  const float* qp_b = (const float*)d_in[4];
  const float* inw  = (const float*)d_in[5];
  const float* inb  = (const float*)d_in[6];
  const float* outw = (const float*)d_in[7];
  const float* outb = (const float*)d_in[8];
  const float* gw   = (const float*)d_in[9];
  const float* gb   = (const float*)d_in[10];
  const float* w1   = (const float*)d_in[11];
  const float* b1   = (const float*)d_in[12];
  const float* lng  = (const float*)d_in[13];
  const float* lnb  = (const float*)d_in[14];
  const float* w2   = (const float*)d_in[15];
  const float* b2   = (const float*)d_in[16];
  const float* ln1g = (const float*)d_in[17];
  const float* ln1b = (const float*)d_in[18];
  const float* ln2g = (const float*)d_in[19];
  const float* ln2b = (const float*)d_in[20];
  float* out = (float*)d_out;
  char* ws = (char*)d_ws;

  const size_t IDX_O   = 0;
  const size_t BCQ_O   = 2048;
  const size_t WCB_O   = 3072;
  const size_t KMAT_O  = 527360;
  const size_t VT_O    = 789504;
  const size_t OUTWB_O = 1051648;
  const size_t GATEW_O = 1182720;
  const size_t INTW1_O = 3804160;
  const size_t INTW2_O = 9047040;
  const size_t QHB_O   = 13241344;
  const size_t QB_O    = 46795776;
  const size_t SB_O    = 55184384;   // t1 region (67 MB)
  const size_t CTX_O   = 122293248;
  const size_t ATTN_O  = 130681856;
  const size_t GATE_O  = 139070464;

  int*    idxb   = (int*)(ws + IDX_O);
  float*  bcq    = (float*)(ws + BCQ_O);
  __bf16* wcb    = (__bf16*)(ws + WCB_O);
  __bf16* kmat   = (__bf16*)(ws + KMAT_O);
  __bf16* vt     = (__bf16*)(ws + VT_O);
  __bf16* outwb  = (__bf16*)(ws + OUTWB_O);
  __bf16* gatewb = (__bf16*)(ws + GATEW_O);
  __bf16* intw1b = (__bf16*)(ws + INTW1_O);
  __bf16* intw2b = (__bf16*)(ws + INTW2_O);
  __bf16* qhb    = (__bf16*)(ws + QHB_O);
  __bf16* gib    = (__bf16*)(ws + QHB_O);   // reuse: qh_bf dead after t1 GEMM
  __bf16* qb     = (__bf16*)(ws + QB_O);
  __bf16* t1b    = (__bf16*)(ws + SB_O);
  __bf16* ctxb   = (__bf16*)(ws + CTX_O);
  __bf16* attnb  = (__bf16*)(ws + ATTN_O);
  __bf16* gateb  = (__bf16*)(ws + GATE_O);
  const __bf16* nullb = nullptr;

  // 1) convert qh + big weights to bf16
  cvt_kernel<<<22336, 256, 0, stream>>>(qh, outw, gw, w1, w2,
                                        qhb, outwb, gatewb, intw1b, intw2b);
  // 2) top-512
  topk_kernel<<<1, 256, 0, stream>>>(sel, idxb);
  // 3) folded Q-projection weight (with 1/8 softmax scale)
  wc_build<<<256, 256, 0, stream>>>(qp_w, qp_b, inw, inb, wcb, bcq);
  // 4) gather + LN + K,Vt
  kv_build<<<512, 256, 0, stream>>>(idxb, memk, inw, inb, ln1g, ln1b, kmat, vt);
  // 5) Q = qh_bf @ Wc^T + bcq   [16384 x 256], K=1024 (BM=64: 512 blocks)
  gemm_kernel<64, 128, 0><<<dim3(256, 2, 1), 256, 0, stream>>>(
      qhb, 1024, 1024, nullb, 0, wcb, 1024, bcq, nullb, qb, 256, 1024, 0, 0, 0);
  // 6) flash attention: ctx = softmax(Q K^T) V   (scale folded into Q)
  flash_kernel<<<dim3(256, 4, 1), 256, 0, stream>>>(qb, kmat, vt, ctxb);
  // 7) attn_out = ctx @ out_w^T + out_b  [16384 x 256], K=256
  gemm_kernel<64, 128, 0><<<dim3(256, 2, 1), 256, 0, stream>>>(
      ctxb, 256, 256, nullb, 0, outwb, 256, outb, nullb, attnb, 256, 256, 0, 0, 0);
  // 8) gate = sigmoid([qh,attn] @ gate_w^T + gate_b)  [16384 x 1024], K=1280
  gemm_kernel<128, 128, 2><<<dim3(128, 8, 1), 256, 0, stream>>>(
      qhb, 1024, 1024, attnb, 256, gatewb, 1280, gb, nullb, gateb, 1024, 1280, 0, 0, 0);
  // 9) t1 = [qh,attn] @ int_w1^T + int_b1  [16384 x 2048], K=1280
  gemm_kernel<128, 128, 0><<<dim3(128, 16, 1), 256, 0, stream>>>(
      qhb, 1024, 1024, attnb, 256, intw1b, 1280, b1, nullb, t1b, 2048, 1280, 0, 0, 0);
  // 10) h = gelu(LN(t1)) in place
  ln_gelu_kernel<<<16384, 256, 0, stream>>>(t1b, lng, lnb);
  // 11) gi = gate * (h @ int_w2^T + int_b2)  [16384 x 1024], K=2048
  gemm_kernel<128, 128, 3><<<dim3(128, 8, 1), 256, 0, stream>>>(
      t1b, 2048, 2048, nullb, 0, intw2b, 2048, b2, gateb, gib, 1024, 2048, 0, 0, 0);
  // 12) out = LN(qh + gi; ln2)
  final_kernel<<<16384, 256, 0, stream>>>(qh, gib, ln2g, ln2b, out);
}

// Round 5
// 600.419 us; speedup vs baseline: 1.0719x; 1.0719x over previous
//
#include <hip/hip_runtime.h>
#include <math.h>

// ---------------------------------------------------------------------------
// MemoryRetriever: B=8, S=2048 (N=16384 rows), H=1024, M=256, NH=4, HD=64,
// NM=4096, K_SEL=512. fp32 I/O, bf16 MFMA internals.
// R5: dispatch-count reduction (12->8): prep merges cvt+topk+wc; flash fuses
//     the Q-projection; gate+int_w1 stacked into one N=3072 GEMM with
//     XCD-aware supertile swizzle on the big GEMMs.
// ---------------------------------------------------------------------------

typedef __bf16 bf16x8 __attribute__((ext_vector_type(8)));
typedef __bf16 bf16x4 __attribute__((ext_vector_type(4)));
typedef float  floatx4 __attribute__((ext_vector_type(4)));

#define NMEM   4096
#define KSEL   512
#define NCVT   22336

__device__ __forceinline__ void gl_lds16(const __bf16* g, __bf16* l) {
  __builtin_amdgcn_global_load_lds(
      (const __attribute__((address_space(1))) void*)g,
      (__attribute__((address_space(3))) void*)l, 16, 0, 0);
}

__device__ __forceinline__ unsigned mapbits(float x) {
  unsigned b = __float_as_uint(x);
  return (b & 0x80000000u) ? ~b : (b | 0x80000000u);
}

// ---------------------------------------------------------------------------
// 1) prep: role-by-block merged kernel.
//    blocks [0, NCVT)          : fp32->bf16 conversion (qh + big weights)
//    blocks [NCVT, NCVT+256)   : Wc = 0.125*(wq@qp_w), bcq (folded Q-proj wt)
//    block  NCVT+256           : top-512 radix-select on selection scores
// ---------------------------------------------------------------------------
__global__ void prep_kernel(const float* __restrict__ s0, const float* __restrict__ s1,
                            const float* __restrict__ s2, const float* __restrict__ s3,
                            const float* __restrict__ s4,
                            __bf16* __restrict__ d0, __bf16* __restrict__ d1,
                            __bf16* __restrict__ d2, __bf16* __restrict__ d3,
                            __bf16* __restrict__ d4,
                            const float* __restrict__ qp_w, const float* __restrict__ qp_b,
                            const float* __restrict__ in_w, const float* __restrict__ in_b,
                            __bf16* __restrict__ Wc, float* __restrict__ bcq,
                            const float* __restrict__ scores, int* __restrict__ idx_out) {
  __shared__ int hist[256];
  __shared__ int s_need;
  __shared__ unsigned s_prefix;
  __shared__ int s_cnt_gt, s_ntie;
  __shared__ int tie[1024];
  const int bx = blockIdx.x, tid = threadIdx.x;

  if (bx < NCVT) {  // ---- cvt role ----
    long q = (long)bx * 256 + tid;
    const long n0 = 16777216 / 4, n1 = 65536 / 4, n2 = 1310720 / 4,
               n3 = 2621440 / 4, n4 = 2097152 / 4;
    const float* s; __bf16* d; long off;
    if (q < n0) { s = s0; d = d0; off = q; }
    else if ((q -= n0) < n1) { s = s1; d = d1; off = q; }
    else if ((q -= n1) < n2) { s = s2; d = d2; off = q; }
    else if ((q -= n2) < n3) { s = s3; d = d3; off = q; }
    else if ((q -= n3) < n4) { s = s4; d = d4; off = q; }
    else return;
    float4 v = ((const float4*)s)[off];
    bf16x4 o;
    o[0] = (__bf16)v.x; o[1] = (__bf16)v.y; o[2] = (__bf16)v.z; o[3] = (__bf16)v.w;
    ((bf16x4*)d)[off] = o;
    return;
  }
  if (bx < NCVT + 256) {  // ---- wc role ----
    int i = bx - NCVT, t = tid;
    const float* wq = in_w + (long)i * 256;
    float a0 = 0, a1 = 0, a2 = 0, a3 = 0;
    for (int s = 0; s < 256; ++s) {
      float wv = wq[s];
      const float* qr = qp_w + (long)s * 1024 + t;
      a0 += wv * qr[0];   a1 += wv * qr[256];
      a2 += wv * qr[512]; a3 += wv * qr[768];
    }
    __bf16* wr = Wc + (long)i * 1024 + t;
    wr[0]   = (__bf16)(0.125f * a0); wr[256] = (__bf16)(0.125f * a1);
    wr[512] = (__bf16)(0.125f * a2); wr[768] = (__bf16)(0.125f * a3);
    if (t == 0) {
      float s = in_b[i];
      for (int j = 0; j < 256; ++j) s += wq[j] * qp_b[j];
      bcq[i] = 0.125f * s;
    }
    return;
  }
  // ---- topk role (single block) ----
  const int n = NMEM, k = KSEL;
  if (tid == 0) { s_need = k; s_prefix = 0; s_cnt_gt = 0; s_ntie = 0; }
  __syncthreads();
  for (int pass = 0; pass < 4; ++pass) {
    hist[tid] = 0;
    __syncthreads();
    int shift = 24 - 8 * pass;
    unsigned pref = s_prefix;
    for (int i = tid; i < n; i += 256) {
      unsigned u = mapbits(scores[i]);
      bool in = (pass == 0) || ((u >> (shift + 8)) == pref);
      if (in) atomicAdd(&hist[(u >> shift) & 255], 1);
    }
    __syncthreads();
    if (tid == 0) {
      int need = s_need, above = 0, b = 255;
      for (;; --b) {
        int c = hist[b];
        if (above + c >= need) { s_need = need - above; break; }
        above += c;
      }
      s_prefix = (s_prefix << 8) | (unsigned)b;
    }
    __syncthreads();
  }
  unsigned T = s_prefix;
  int need = s_need;
  for (int i = tid; i < n; i += 256) {
    unsigned u = mapbits(scores[i]);
    if (u > T) { int p = atomicAdd(&s_cnt_gt, 1); idx_out[p] = i; }
    else if (u == T) { int t = atomicAdd(&s_ntie, 1); if (t < 1024) tie[t] = i; }
  }
  __syncthreads();
  int base = s_cnt_gt;
  int nt = s_ntie < 1024 ? s_ntie : 1024;
  for (int j = tid; j < nt; j += 256) {
    int my = tie[j], rank = 0;
    for (int l = 0; l < nt; ++l) rank += (tie[l] < my) ? 1 : 0;
    if (rank < need) idx_out[base + rank] = my;
  }
}

// ---------------------------------------------------------------------------
// 2) gather + LN(ln1) + K / V projections. K row-major [512,256] bf16;
//    V transposed: Vt[h][d][key] = [4][64][512] bf16.
// ---------------------------------------------------------------------------
__global__ void kv_build(const int* __restrict__ idx, const float* __restrict__ mem_keys,
                         const float* __restrict__ in_w, const float* __restrict__ in_b,
                         const float* __restrict__ ln1g, const float* __restrict__ ln1b,
                         __bf16* __restrict__ Kmat, __bf16* __restrict__ Vt) {
  int r = blockIdx.x, t = threadIdx.x;  // 512 blocks x 256 threads
  int lane = t & 63, wave = t >> 6;
  __shared__ float wred[8];
  __shared__ float m[256];
  int row = idx[r];
  float x = mem_keys[(long)row * 256 + t];
  float s = x;
  #pragma unroll
  for (int o = 32; o > 0; o >>= 1) s += __shfl_xor(s, o);
  if (lane == 0) wred[wave] = s;
  __syncthreads();
  float mu = (wred[0] + wred[1] + wred[2] + wred[3]) / 256.0f;
  float e = x - mu;
  s = e * e;
  #pragma unroll
  for (int o = 32; o > 0; o >>= 1) s += __shfl_xor(s, o);
  if (lane == 0) wred[4 + wave] = s;
  __syncthreads();
  float rstd = rsqrtf((wred[4] + wred[5] + wred[6] + wred[7]) / 256.0f + 1e-5f);
  m[t] = e * rstd * ln1g[t] + ln1b[t];
  __syncthreads();
  float ka = 0.f, va = 0.f;
  const float* wk = in_w + (long)(256 + t) * 256;
  const float* wv = in_w + (long)(512 + t) * 256;
  #pragma unroll 4
  for (int i = 0; i < 256; i += 4) {
    float4 wkv = *(const float4*)(wk + i);
    float4 wvv = *(const float4*)(wv + i);
    ka += m[i] * wkv.x + m[i + 1] * wkv.y + m[i + 2] * wkv.z + m[i + 3] * wkv.w;
    va += m[i] * wvv.x + m[i + 1] * wvv.y + m[i + 2] * wvv.z + m[i + 3] * wvv.w;
  }
  ka += in_b[256 + t]; va += in_b[512 + t];
  Kmat[(long)r * 256 + t] = (__bf16)ka;
  Vt[(long)(t >> 6) * (64 * 512) + (long)(t & 63) * 512 + r] = (__bf16)va;
}

// ---------------------------------------------------------------------------
// 3) m97-style bf16 MFMA GEMM with XOR-swizzled LDS + optional XCD supertile
//    swizzle (SWIZ: 1D grid, id%8 -> x-subgroup so each XCD reuses one A
//    row-tile across all column-tiles in its L2).
//    EPI: 0=bias, 1=none, 3=bias then *gmul, 4=split N (col<1024: sigmoid
//    -> C; else: bias2 -> C2).
// ---------------------------------------------------------------------------
template <int BM, int BN, int EPI, bool SWIZ>
__launch_bounds__(256, 4)
__global__ void gemm_kernel(const __bf16* __restrict__ X1, int ldx1, int K1,
                            const __bf16* __restrict__ X2, int ldx2,
                            const __bf16* __restrict__ W, int ldw,
                            const float* __restrict__ bias,
                            const float* __restrict__ bias2,
                            const __bf16* __restrict__ gmul,
                            __bf16* __restrict__ C, int ldc,
                            __bf16* __restrict__ C2, int ldc2,
                            int Ktot, int nY,
                            long sXz, long sWz, long sCz) {
  constexpr int BK = 64;
  __shared__ __bf16 As[BM * BK];
  __shared__ __bf16 Bs[BN * BK];
  const int tid = threadIdx.x;
  const int lane = tid & 63, wave = tid >> 6;
  const int wm = wave >> 1, wn = wave & 1;
  constexpr int FM = (BM / 2) / 16, FN = (BN / 2) / 16;
  floatx4 acc[FM][FN];
  #pragma unroll
  for (int i = 0; i < FM; ++i)
    #pragma unroll
    for (int j = 0; j < FN; ++j)
      #pragma unroll
      for (int r = 0; r < 4; ++r) acc[i][j][r] = 0.0f;

  int bx, by;
  if (SWIZ) {
    int lin = blockIdx.x;
    int sx = lin & 7, rest = lin >> 3;
    by = rest % nY; bx = (rest / nY) * 8 + sx;
  } else {
    bx = blockIdx.x; by = blockIdx.y;
  }
  const long z = blockIdx.z;
  const __bf16* x1 = X1 + z * sXz;
  const __bf16* w  = W + z * sWz;
  __bf16* c = C + z * sCz;
  const long row0 = (long)bx * BM;
  const int col0 = by * BN;
  const int nKt = Ktot / BK;
  const int srow = lane >> 3;                    // 0..7 : row within 8-row chunk
  const int scol = ((lane & 7) ^ srow) * 8;      // XOR-swizzled col chunk

  for (int kt = 0; kt < nKt; ++kt) {
    const int k0 = kt * BK;
    const __bf16* xb; long xld; int kx;  // segment select (wave-uniform)
    if (k0 < K1) { xb = x1; xld = ldx1; kx = k0; }
    else         { xb = X2; xld = ldx2; kx = k0 - K1; }
    #pragma unroll
    for (int i = 0; i < BM / 32; ++i) {  // A: chunks of 8 rows x 64 cols
      int chunk = wave * (BM / 32) + i;
      const __bf16* g = xb + (row0 + chunk * 8 + srow) * xld + kx + scol;
      gl_lds16(g, As + chunk * 512);
    }
    #pragma unroll
    for (int i = 0; i < BN / 32; ++i) {
      int chunk = wave * (BN / 32) + i;
      const __bf16* g = w + (long)(col0 + chunk * 8 + srow) * ldw + k0 + scol;
      gl_lds16(g, Bs + chunk * 512);
    }
    __syncthreads();
    #pragma unroll
    for (int kk = 0; kk < 2; ++kk) {
      bf16x8 a[FM], b[FN];
      const int ccq = kk * 4 + (lane >> 4);      // col-chunk index 0..7
      #pragma unroll
      for (int fm = 0; fm < FM; ++fm) {
        const int r = wm * (BM / 2) + fm * 16 + (lane & 15);
        a[fm] = *(const bf16x8*)(As + r * BK + ((ccq ^ (r & 7)) << 3));
      }
      #pragma unroll
      for (int fn = 0; fn < FN; ++fn) {
        const int r = wn * (BN / 2) + fn * 16 + (lane & 15);
        b[fn] = *(const bf16x8*)(Bs + r * BK + ((ccq ^ (r & 7)) << 3));
      }
      #pragma unroll
      for (int fm = 0; fm < FM; ++fm)
        #pragma unroll
        for (int fn = 0; fn < FN; ++fn)
          acc[fm][fn] = __builtin_amdgcn_mfma_f32_16x16x32_bf16(a[fm], b[fn], acc[fm][fn], 0, 0, 0);
    }
    __syncthreads();
  }
  // epilogue: C/D layout col = lane&15, row = (lane>>4)*4 + r
  #pragma unroll
  for (int fn = 0; fn < FN; ++fn) {
    const int col = col0 + wn * (BN / 2) + fn * 16 + (lane & 15);
    float bv;
    if (EPI == 1) bv = 0.0f;
    else if (EPI == 4) bv = (col < 1024) ? bias[col] : bias2[col - 1024];
    else bv = bias[col];
    #pragma unroll
    for (int fm = 0; fm < FM; ++fm) {
      #pragma unroll
      for (int r = 0; r < 4; ++r) {
        long row = row0 + wm * (BM / 2) + fm * 16 + (lane >> 4) * 4 + r;
        float v = acc[fm][fn][r] + bv;
        if (EPI == 3) v *= (float)gmul[row * (long)ldc + col];
        if (EPI == 4) {
          if (col < 1024) {
            v = 1.0f / (1.0f + __expf(-v));
            C[row * (long)ldc + col] = (__bf16)v;
          } else {
            C2[row * (long)ldc2 + (col - 1024)] = (__bf16)v;
          }
        } else {
          c[row * (long)ldc + col] = (__bf16)v;
        }
      }
    }
  }
}

// ---------------------------------------------------------------------------
// 4) Flash attention with fused Q-projection.  Per (64-row tile, head):
//    Q = qh[rows, 0:1024] @ Wc[h*64:+64, :]^T + bcq  (scale pre-folded),
//    then S = Q·K^T, online softmax, O = P·V over 4 chunks of 128 keys.
//    Q-build stages A into Ks and W into Vs (BK=128 as two 64-halves),
//    writes Q to Qs in swizzled A-layout. All LDS XOR-swizzled (2-way=free).
// ---------------------------------------------------------------------------
__launch_bounds__(256, 2)
__global__ void flash_kernel(const __bf16* __restrict__ qh, const __bf16* __restrict__ Wc,
                             const float* __restrict__ bcq,
                             const __bf16* __restrict__ Km, const __bf16* __restrict__ Vt,
                             __bf16* __restrict__ Ctx) {
  __shared__ __bf16 Qs[64 * 64];    //  8 KB
  __shared__ __bf16 Ks[128 * 64];   // 16 KB
  __shared__ __bf16 Vs[64 * 128];   // 16 KB
  __shared__ __bf16 Ps[64 * 128];   // 16 KB
  __shared__ float mpart[2][64], spart[2][64];
  __shared__ float m_run[64], l_run[64];
  const int tid = threadIdx.x, lane = tid & 63, wave = tid >> 6;
  const int wm = wave >> 1, wn = wave & 1;
  const long row0 = (long)blockIdx.x * 64;
  const int h = blockIdx.y;
  const int srow = lane >> 3, scc = lane & 7;
  const int q4 = lane >> 4, l15 = lane & 15;

  if (tid < 64) { m_run[tid] = -3e38f; l_run[tid] = 0.f; }

  // ---- Q build: 64x64 tile, K=1024 in 8 iters of BK=128 (two 64-halves) ----
  floatx4 qacc[2][2];
  #pragma unroll
  for (int fm = 0; fm < 2; ++fm)
    #pragma unroll
    for (int fn = 0; fn < 2; ++fn)
      #pragma unroll
      for (int r = 0; r < 4; ++r) qacc[fm][fn][r] = 0.f;
  for (int kt = 0; kt < 8; ++kt) {
    #pragma unroll
    for (int jh = 0; jh < 2; ++jh) {
      #pragma unroll
      for (int i = 0; i < 2; ++i) {
        int chunk = wave * 2 + i;      // 0..7, 8 rows each
        int r = chunk * 8 + srow;
        int kg = kt * 128 + jh * 64 + ((scc ^ (r & 7)) << 3);
        gl_lds16(qh + (row0 + r) * 1024 + kg, Ks + jh * 4096 + chunk * 512);
        gl_lds16(Wc + (long)(h * 64 + r) * 1024 + kg, Vs + jh * 4096 + chunk * 512);
      }
    }
    __syncthreads();
    #pragma unroll
    for (int jh = 0; jh < 2; ++jh)
      #pragma unroll
      for (int kk = 0; kk < 2; ++kk) {
        bf16x8 a[2], b[2];
        const int ccq = kk * 4 + q4;
        #pragma unroll
        for (int fm = 0; fm < 2; ++fm) {
          const int r = wm * 32 + fm * 16 + l15;
          a[fm] = *(const bf16x8*)(Ks + jh * 4096 + r * 64 + ((ccq ^ (r & 7)) << 3));
        }
        #pragma unroll
        for (int fn = 0; fn < 2; ++fn) {
          const int r = wn * 32 + fn * 16 + l15;
          b[fn] = *(const bf16x8*)(Vs + jh * 4096 + r * 64 + ((ccq ^ (r & 7)) << 3));
        }
        #pragma unroll
        for (int fm = 0; fm < 2; ++fm)
          #pragma unroll
          for (int fn = 0; fn < 2; ++fn)
            qacc[fm][fn] = __builtin_amdgcn_mfma_f32_16x16x32_bf16(a[fm], b[fn], qacc[fm][fn], 0, 0, 0);
      }
    __syncthreads();
  }
  // write Q (+bias) to Qs in swizzled A-layout
  #pragma unroll
  for (int fm = 0; fm < 2; ++fm)
    #pragma unroll
    for (int fn = 0; fn < 2; ++fn)
      #pragma unroll
      for (int r = 0; r < 4; ++r) {
        int row = wm * 32 + fm * 16 + q4 * 4 + r;
        int col = wn * 32 + fn * 16 + l15;
        float v = qacc[fm][fn][r] + bcq[h * 64 + col];
        Qs[row * 64 + (((col >> 3) ^ (row & 7)) << 3) + (col & 7)] = (__bf16)v;
      }
  __syncthreads();

  floatx4 oacc[2][2];
  #pragma unroll
  for (int fm = 0; fm < 2; ++fm)
    #pragma unroll
    for (int fn = 0; fn < 2; ++fn)
      #pragma unroll
      for (int r = 0; r < 4; ++r) oacc[fm][fn][r] = 0.f;

  for (int c = 0; c < 4; ++c) {
    // stage K chunk (128 keys x 64 dims) and V chunk (64 dims x 128 keys)
    #pragma unroll
    for (int i = 0; i < 4; ++i) {
      int chunk = wave * 4 + i;  // 0..15
      int r = chunk * 8 + srow;
      gl_lds16(Km + (long)(c * 128 + r) * 256 + h * 64 + ((scc ^ (r & 7)) << 3),
               Ks + chunk * 512);
    }
    #pragma unroll
    for (int i = 0; i < 4; ++i) {
      int chunk = wave * 4 + i;  // 0..15, 4 d-rows each
      int d = chunk * 4 + q4;
      int cc = l15 ^ (d & 7);
      gl_lds16(Vt + (long)h * 32768 + (long)d * 512 + c * 128 + cc * 8,
               Vs + chunk * 512);
    }
    __syncthreads();

    // S = Q·Kc^T : per wave 32 rows x 64 keys
    floatx4 sacc[2][4];
    #pragma unroll
    for (int fm = 0; fm < 2; ++fm)
      #pragma unroll
      for (int fn = 0; fn < 4; ++fn)
        #pragma unroll
        for (int r = 0; r < 4; ++r) sacc[fm][fn][r] = 0.f;
    #pragma unroll
    for (int kk = 0; kk < 2; ++kk) {
      bf16x8 a[2], b[4];
      const int ccq = kk * 4 + q4;
      #pragma unroll
      for (int fm = 0; fm < 2; ++fm) {
        const int r = wm * 32 + fm * 16 + l15;
        a[fm] = *(const bf16x8*)(Qs + r * 64 + ((ccq ^ (r & 7)) << 3));
      }
      #pragma unroll
      for (int fn = 0; fn < 4; ++fn) {
        const int r = wn * 64 + fn * 16 + l15;
        b[fn] = *(const bf16x8*)(Ks + r * 64 + ((ccq ^ (r & 7)) << 3));
      }
      #pragma unroll
      for (int fm = 0; fm < 2; ++fm)
        #pragma unroll
        for (int fn = 0; fn < 4; ++fn)
          sacc[fm][fn] = __builtin_amdgcn_mfma_f32_16x16x32_bf16(a[fm], b[fn], sacc[fm][fn], 0, 0, 0);
    }
    // per-row partial max over this wave's 64 keys
    #pragma unroll
    for (int fm = 0; fm < 2; ++fm) {
      #pragma unroll
      for (int r = 0; r < 4; ++r) {
        float v = sacc[fm][0][r];
        #pragma unroll
        for (int fn = 1; fn < 4; ++fn) v = fmaxf(v, sacc[fm][fn][r]);
        v = fmaxf(v, __shfl_xor(v, 1)); v = fmaxf(v, __shfl_xor(v, 2));
        v = fmaxf(v, __shfl_xor(v, 4)); v = fmaxf(v, __shfl_xor(v, 8));
        if (l15 == 0) mpart[wn][wm * 32 + fm * 16 + q4 * 4 + r] = v;
      }
    }
    __syncthreads();  // mpart ready

    // phase A: new max, alpha, P, partial row sums
    float nm[2][4], al[2][4], rs[2][4];
    #pragma unroll
    for (int fm = 0; fm < 2; ++fm)
      #pragma unroll
      for (int r = 0; r < 4; ++r) {
        int row = wm * 32 + fm * 16 + q4 * 4 + r;
        float pm = fmaxf(mpart[0][row], mpart[1][row]);
        float mo = m_run[row];
        float x = fmaxf(mo, pm);
        nm[fm][r] = x;
        al[fm][r] = __expf(mo - x);
        rs[fm][r] = 0.f;
      }
    #pragma unroll
    for (int fm = 0; fm < 2; ++fm)
      #pragma unroll
      for (int fn = 0; fn < 4; ++fn)
        #pragma unroll
        for (int r = 0; r < 4; ++r) {
          float p = __expf(sacc[fm][fn][r] - nm[fm][r]);
          rs[fm][r] += p;
          int row = wm * 32 + fm * 16 + q4 * 4 + r;
          int key = wn * 64 + fn * 16 + l15;
          Ps[row * 128 + (((key >> 3) ^ (row & 7)) << 3) + (key & 7)] = (__bf16)p;
        }
    #pragma unroll
    for (int fm = 0; fm < 2; ++fm)
      #pragma unroll
      for (int r = 0; r < 4; ++r) {
        float v = rs[fm][r];
        v += __shfl_xor(v, 1); v += __shfl_xor(v, 2);
        v += __shfl_xor(v, 4); v += __shfl_xor(v, 8);
        if (l15 == 0) spart[wn][wm * 32 + fm * 16 + q4 * 4 + r] = v;
      }
    __syncthreads();  // spart + Ps ready

    // phase B: update running stats, rescale O, O += P·Vc
    #pragma unroll
    for (int fm = 0; fm < 2; ++fm)
      #pragma unroll
      for (int r = 0; r < 4; ++r) {
        int row = wm * 32 + fm * 16 + q4 * 4 + r;
        if (wn == 0 && l15 == 0) {
          m_run[row] = nm[fm][r];
          l_run[row] = l_run[row] * al[fm][r] + spart[0][row] + spart[1][row];
        }
        #pragma unroll
        for (int fn = 0; fn < 2; ++fn) oacc[fm][fn][r] *= al[fm][r];
      }
    #pragma unroll
    for (int step = 0; step < 4; ++step) {
      bf16x8 a[2], b[2];
      const int ccq = step * 4 + q4;
      #pragma unroll
      for (int fm = 0; fm < 2; ++fm) {
        const int r = wm * 32 + fm * 16 + l15;
        a[fm] = *(const bf16x8*)(Ps + r * 128 + ((ccq ^ (r & 7)) << 3));
      }
      #pragma unroll
      for (int fn = 0; fn < 2; ++fn) {
        const int rv = wn * 32 + fn * 16 + l15;
        b[fn] = *(const bf16x8*)(Vs + rv * 128 + ((ccq ^ (rv & 7)) << 3));
      }
      #pragma unroll
      for (int fm = 0; fm < 2; ++fm)
        #pragma unroll
        for (int fn = 0; fn < 2; ++fn)
          oacc[fm][fn] = __builtin_amdgcn_mfma_f32_16x16x32_bf16(a[fm], b[fn], oacc[fm][fn], 0, 0, 0);
    }
    __syncthreads();
  }
  // epilogue: ctx = O / l
  #pragma unroll
  for (int fm = 0; fm < 2; ++fm)
    #pragma unroll
    for (int r = 0; r < 4; ++r) {
      int row = wm * 32 + fm * 16 + q4 * 4 + r;
      float inv = 1.0f / l_run[row];
      #pragma unroll
      for (int fn = 0; fn < 2; ++fn) {
        int col = wn * 32 + fn * 16 + l15;
        Ctx[(row0 + row) * 256 + h * 64 + col] = (__bf16)(oacc[fm][fn][r] * inv);
      }
    }
}

// ---------------------------------------------------------------------------
// 5) LN(int_ln) + gelu (tanh form), in-place on t1 rows of 2048.
// ---------------------------------------------------------------------------
__global__ void ln_gelu_kernel(__bf16* __restrict__ T1, const float* __restrict__ g,
                               const float* __restrict__ b) {
  long row = blockIdx.x; int t = threadIdx.x;  // 256 threads, 8 elems each
  int lane = t & 63, wave = t >> 6;
  __shared__ float wred[8];
  __bf16* p = T1 + row * 2048 + t * 8;
  bf16x8 v = *(const bf16x8*)p;
  float f[8], s = 0.f;
  #pragma unroll
  for (int j = 0; j < 8; ++j) { f[j] = (float)v[j]; s += f[j]; }
  #pragma unroll
  for (int o = 32; o > 0; o >>= 1) s += __shfl_xor(s, o);
  if (lane == 0) wred[wave] = s;
  __syncthreads();
  float mu = (wred[0] + wred[1] + wred[2] + wred[3]) / 2048.0f;
  s = 0.f;
  #pragma unroll
  for (int j = 0; j < 8; ++j) { f[j] -= mu; s += f[j] * f[j]; }
  #pragma unroll
  for (int o = 32; o > 0; o >>= 1) s += __shfl_xor(s, o);
  if (lane == 0) wred[4 + wave] = s;
  __syncthreads();
  float rstd = rsqrtf((wred[4] + wred[5] + wred[6] + wred[7]) / 2048.0f + 1e-5f);
  float4 g0 = *(const float4*)(g + t * 8), g1 = *(const float4*)(g + t * 8 + 4);
  float4 b0 = *(const float4*)(b + t * 8), b1 = *(const float4*)(b + t * 8 + 4);
  float gg[8] = { g0.x, g0.y, g0.z, g0.w, g1.x, g1.y, g1.z, g1.w };
  float bb[8] = { b0.x, b0.y, b0.z, b0.w, b1.x, b1.y, b1.z, b1.w };
  bf16x8 o8;
  #pragma unroll
  for (int j = 0; j < 8; ++j) {
    float y = f[j] * rstd * gg[j] + bb[j];
    float u = 1.5957691216057308f * (y + 0.044715f * y * y * y);
    o8[j] = (__bf16)(y / (1.0f + __expf(-u)));
  }
  *(bf16x8*)p = o8;
}

// ---------------------------------------------------------------------------
// 6) out = LN(qh + gi; ln2)  (fp32 out), gi = gate*integrated (pre-fused)
// ---------------------------------------------------------------------------
__global__ void final_kernel(const float* __restrict__ qh, const __bf16* __restrict__ gi,
                             const float* __restrict__ g, const float* __restrict__ b,
                             float* __restrict__ out) {
  long row = blockIdx.x; int t = threadIdx.x;  // 256 threads, 4 elems each
  int lane = t & 63, wave = t >> 6;
  __shared__ float wred[8];
  long base = row * 1024 + t * 4;
  float4 q = *(const float4*)(qh + base);
  bf16x4 gv = *(const bf16x4*)(gi + base);
  float f[4] = { q.x + (float)gv[0], q.y + (float)gv[1],
                 q.z + (float)gv[2], q.w + (float)gv[3] };
  float s = f[0] + f[1] + f[2] + f[3];
  #pragma unroll
  for (int o = 32; o > 0; o >>= 1) s += __shfl_xor(s, o);
  if (lane == 0) wred[wave] = s;
  __syncthreads();
  float mu = (wred[0] + wred[1] + wred[2] + wred[3]) / 1024.0f;
  s = 0.f;
  #pragma unroll
  for (int j = 0; j < 4; ++j) { f[j] -= mu; s += f[j] * f[j]; }
  #pragma unroll
  for (int o = 32; o > 0; o >>= 1) s += __shfl_xor(s, o);
  if (lane == 0) wred[4 + wave] = s;
  __syncthreads();
  float rstd = rsqrtf((wred[4] + wred[5] + wred[6] + wred[7]) / 1024.0f + 1e-5f);
  float4 gv4 = *(const float4*)(g + t * 4);
  float4 bv4 = *(const float4*)(b + t * 4);
  float4 ov;
  ov.x = f[0] * rstd * gv4.x + bv4.x;
  ov.y = f[1] * rstd * gv4.y + bv4.y;
  ov.z = f[2] * rstd * gv4.z + bv4.z;
  ov.w = f[3] * rstd * gv4.w + bv4.w;
  *(float4*)(out + base) = ov;
}

// ---------------------------------------------------------------------------
// launch
// ---------------------------------------------------------------------------
extern "C" void kernel_launch(void* const* d_in, const int* in_sizes, int n_in,
                              void* d_out, int out_size, void* d_ws, size_t ws_size,
                              hipStream_t stream) {
  const float* qh   = (const float*)d_in[0];
  const float* memk = (const float*)d_in[1];
  const float* sel  = (const float*)d_in[2];
  const float* qp_w = (const float*)d_in[3];
  const float* qp_b = (const float*)d_in[4];
  const float* inw  = (const float*)d_in[5];
  const float* inb  = (const float*)d_in[6];
  const float* outw = (const float*)d_in[7];
  const float* outb = (const float*)d_in[8];
  const float* gw   = (const float*)d_in[9];
  const float* gb   = (const float*)d_in[10];
  const float* w1   = (const float*)d_in[11];
  const float* b1   = (const float*)d_in[12];
  const float* lng  = (const float*)d_in[13];
  const float* lnb  = (const float*)d_in[14];
  const float* w2   = (const float*)d_in[15];
  const float* b2   = (const float*)d_in[16];
  const float* ln1g = (const float*)d_in[17];
  const float* ln1b = (const float*)d_in[18];
  const float* ln2g = (const float*)d_in[19];
  const float* ln2b = (const float*)d_in[20];
  float* out = (float*)d_out;
  char* ws = (char*)d_ws;

  // arena: gatewb and intw1b are contiguous => combined [3072 x 1280] weight
  const size_t IDX_O   = 0;
  const size_t BCQ_O   = 2048;
  const size_t WCB_O   = 3072;
  const size_t KMAT_O  = 527360;
  const size_t VT_O    = 789504;
  const size_t OUTWB_O = 1051648;
  const size_t GATEW_O = 1182720;    // [1024 x 1280] bf16
  const size_t INTW1_O = 3804160;    // [2048 x 1280] bf16 (= GATEW_O + size)
  const size_t INTW2_O = 9047040;
  const size_t QHB_O   = 13241344;   // qh_bf; later reused as gi
  const size_t SB_O    = 55184384;   // t1 region (67 MB)
  const size_t CTX_O   = 122293248;
  const size_t ATTN_O  = 130681856;
  const size_t GATE_O  = 139070464;

  int*    idxb   = (int*)(ws + IDX_O);
  float*  bcq    = (float*)(ws + BCQ_O);
  __bf16* wcb    = (__bf16*)(ws + WCB_O);
  __bf16* kmat   = (__bf16*)(ws + KMAT_O);
  __bf16* vt     = (__bf16*)(ws + VT_O);
  __bf16* outwb  = (__bf16*)(ws + OUTWB_O);
  __bf16* gatewb = (__bf16*)(ws + GATEW_O);
  __bf16* intw1b = (__bf16*)(ws + INTW1_O);
  __bf16* intw2b = (__bf16*)(ws + INTW2_O);
  __bf16* qhb    = (__bf16*)(ws + QHB_O);
  __bf16* gib    = (__bf16*)(ws + QHB_O);   // reuse: qh_bf dead after combined GEMM
  __bf16* t1b    = (__bf16*)(ws + SB_O);
  __bf16* ctxb   = (__bf16*)(ws + CTX_O);
  __bf16* attnb  = (__bf16*)(ws + ATTN_O);
  __bf16* gateb  = (__bf16*)(ws + GATE_O);
  __bf16* nullb  = nullptr;
  const float* nullf = nullptr;

  // 1) prep: cvt (22336 blocks) + wc (256) + topk (1)
  prep_kernel<<<NCVT + 257, 256, 0, stream>>>(
      qh, outw, gw, w1, w2, qhb, outwb, gatewb, intw1b, intw2b,
      qp_w, qp_b, inw, inb, wcb, bcq, sel, idxb);
  // 2) gather + LN + K,Vt
  kv_build<<<512, 256, 0, stream>>>(idxb, memk, inw, inb, ln1g, ln1b, kmat, vt);
  // 3) flash attention with fused Q-projection
  flash_kernel<<<dim3(256, 4, 1), 256, 0, stream>>>(qhb, wcb, bcq, kmat, vt, ctxb);
  // 4) attn_out = ctx @ out_w^T + out_b  [16384 x 256], K=256
  gemm_kernel<64, 128, 0, false><<<dim3(256, 2, 1), 256, 0, stream>>>(
      ctxb, 256, 256, nullb, 0, outwb, 256, outb, nullf, nullb,
      attnb, 256, nullb, 0, 256, 2, 0, 0, 0);
  // 5) combined: [gate | t1] = [qh,attn] @ [gate_w;int_w1]^T  [16384 x 3072]
  gemm_kernel<128, 128, 4, true><<<dim3(128 * 24, 1, 1), 256, 0, stream>>>(
      qhb, 1024, 1024, attnb, 256, gatewb, 1280, gb, b1, nullb,
      gateb, 1024, t1b, 2048, 1280, 24, 0, 0, 0);
  // 6) h = gelu(LN(t1)) in place
  ln_gelu_kernel<<<16384, 256, 0, stream>>>(t1b, lng, lnb);
  // 7) gi = gate * (h @ int_w2^T + int_b2)  [16384 x 1024], K=2048
  gemm_kernel<128, 128, 3, true><<<dim3(128 * 8, 1, 1), 256, 0, stream>>>(
      t1b, 2048, 2048, nullb, 0, intw2b, 2048, b2, nullf, gateb,
      gib, 1024, nullb, 0, 2048, 8, 0, 0, 0);
  // 8) out = LN(qh + gi; ln2)
  final_kernel<<<16384, 256, 0, stream>>>(qh, gib, ln2g, ln2b, out);
}